// Round 6
// baseline (702.436 us; speedup 1.0000x reference)
//
#include <hip/hip_runtime.h>

#define D 64
#define KCODES 512
#define BLOCK 256
#define RPB 64           // rows per block (4 waves x 16 rows) -> grid 2048 = 8 blocks/CU
#define CHUNK 64         // codes staged in LDS per iteration
#define NCHUNK (KCODES / CHUNK)
#define CBS 72           // LDS stride (shorts) per code row: structural-min banking

typedef short  short8  __attribute__((ext_vector_type(8)));
typedef float  f32x4   __attribute__((ext_vector_type(4)));

__device__ __forceinline__ unsigned short bf16rne(float f) {
    union { float f; unsigned u; } a; a.f = f;
    unsigned r = a.u + 0x7FFFu + ((a.u >> 16) & 1u);
    return (unsigned short)(r >> 16);
}

// prep: cc[k]=||c_k||^2 (round-1 fma order) + bf16(-2c) into ws. hi only.
__global__ __launch_bounds__(256) void vq_prep(const float* __restrict__ cb,
                                               unsigned short* __restrict__ wh,
                                               float* __restrict__ cc) {
    const int k = blockIdx.x * 256 + threadIdx.x;
    if (k >= KCODES) return;
    const float4* cv = (const float4*)(cb + k * D);
    float s = 0.f;
    #pragma unroll
    for (int db = 0; db < 16; ++db) {
        float4 q = cv[db];
        s = fmaf(q.x, q.x, s); s = fmaf(q.y, q.y, s);
        s = fmaf(q.z, q.z, s); s = fmaf(q.w, q.w, s);
        wh[k * D + db * 4 + 0] = bf16rne(-2.f * q.x);
        wh[k * D + db * 4 + 1] = bf16rne(-2.f * q.y);
        wh[k * D + db * 4 + 2] = bf16rne(-2.f * q.z);
        wh[k * D + db * 4 + 3] = bf16rne(-2.f * q.w);
    }
    cc[k] = s;
}

__global__ __launch_bounds__(BLOCK, 8) void vq_mfma(const float* __restrict__ x,
                                                    const float* __restrict__ cb,
                                                    const unsigned short* __restrict__ wh,
                                                    const float* __restrict__ ccg,
                                                    float* __restrict__ out) {
    __shared__ unsigned short s_cbh[CHUNK * CBS];   // 9 KB
    __shared__ float s_cc[KCODES];                  // 2 KB
    __shared__ float s_xx[RPB];
    __shared__ int   s_bi[RPB];
    __shared__ int   s_flag[RPB];
    __shared__ int   s_nflag;

    const int t    = threadIdx.x;
    const int w    = t >> 6;
    const int lane = t & 63;
    const int quad = lane >> 4;
    const int col  = lane & 15;
    const float4* xv4  = (const float4*)x;
    const float4* cbv4 = (const float4*)cb;

    if (t == 0) s_nflag = 0;

    // A-fragment (validated r4/r5 layout): m = lane&15, d = kt*32 + quad*8 + j.
    // Wave w owns rows w*16 .. w*16+15. hi-only -> 8 VGPRs of fragment state.
    short8 xh[2];
    {
        const size_t row = (size_t)blockIdx.x * RPB + w * 16 + col;
        #pragma unroll
        for (int kt = 0; kt < 2; ++kt) {
            float4 p0 = xv4[row * 16 + kt * 8 + quad * 2];
            float4 p1 = xv4[row * 16 + kt * 8 + quad * 2 + 1];
            short8 h;
            h[0] = (short)bf16rne(p0.x); h[1] = (short)bf16rne(p0.y);
            h[2] = (short)bf16rne(p0.z); h[3] = (short)bf16rne(p0.w);
            h[4] = (short)bf16rne(p1.x); h[5] = (short)bf16rne(p1.y);
            h[6] = (short)bf16rne(p1.z); h[7] = (short)bf16rne(p1.w);
            xh[kt] = h;
        }
    }

    // wave 0: xx per row (round-1 exact order, reused by exact path);
    // waves 1-2: stage cc. x tile is L1/L2-hot from the fragment loads.
    if (t < RPB) {
        const size_t gr = (size_t)blockIdx.x * RPB + t;
        float s = 0.f;
        #pragma unroll
        for (int db = 0; db < 16; ++db) {
            float4 q = xv4[gr * 16 + db];
            s = fmaf(q.x, q.x, s); s = fmaf(q.y, q.y, s);
            s = fmaf(q.z, q.z, s); s = fmaf(q.w, q.w, s);
        }
        s_xx[t] = s;
    } else if (t < RPB + 128) {
        const int k4 = (t - RPB) * 4;
        *(float4*)&s_cc[k4] = *(const float4*)&ccg[k4];
    }
    __syncthreads();

    // xx for the C/D rows this lane holds: row = quad*4 + r (validated r4/r5)
    float xxr[4];
    #pragma unroll
    for (int r = 0; r < 4; ++r) xxr[r] = s_xx[w * 16 + quad * 4 + r];

    float best[4], second[4]; int bis[4];
    #pragma unroll
    for (int i = 0; i < 4; ++i) { best[i] = __builtin_inff(); second[i] = __builtin_inff(); bis[i] = 0; }

    for (int c = 0; c < NCHUNK; ++c) {
        if (c) __syncthreads();
        // stage 64 codes: 512 x 16B units, 2 per thread, coalesced reads
        const short8* gh = (const short8*)wh + c * (CHUNK * D / 8);
        #pragma unroll
        for (int i = 0; i < 2; ++i) {
            const int u = i * 256 + t;
            const int lc = u >> 3, seg = u & 7;
            *(short8*)&s_cbh[lc * CBS + seg * 8] = gh[u];
        }
        __syncthreads();

        #pragma unroll 2
        for (int ct = 0; ct < CHUNK / 16; ++ct) {
            const int lc = ct * 16 + col;            // B layout: n = lane&15
            short8 ch0 = *(const short8*)&s_cbh[lc * CBS + quad * 8];
            short8 ch1 = *(const short8*)&s_cbh[lc * CBS + 32 + quad * 8];
            const int   kglob = c * CHUNK + ct * 16 + col;
            const float cck   = s_cc[kglob];

            f32x4 acc;
            #pragma unroll
            for (int r = 0; r < 4; ++r) acc[r] = xxr[r] + cck;
            // dist ~= (xx + cc) + sum(bf16(-2c) * bf16(x)); error 6sig ~ 8e-3,
            // anything within tau=1.5e-2 of best goes to the exact fp32 path.
            acc = __builtin_amdgcn_mfma_f32_16x16x32_bf16(xh[0], ch0, acc, 0, 0, 0);
            acc = __builtin_amdgcn_mfma_f32_16x16x32_bf16(xh[1], ch1, acc, 0, 0, 0);

            #pragma unroll
            for (int r = 0; r < 4; ++r) {
                const float dist = acc[r];
                second[r] = fminf(second[r], fmaxf(best[r], dist));
                if (dist < best[r]) { best[r] = dist; bis[r] = kglob; }
            }
        }
    }

    // argmin across the 16 code-lanes per row (validated r4/r5)
    #pragma unroll
    for (int r = 0; r < 4; ++r) {
        float b = best[r], s2 = second[r]; int bi = bis[r];
        #pragma unroll
        for (int off = 1; off < 16; off <<= 1) {
            float ob  = __shfl_xor(b, off);
            int   obi = __shfl_xor(bi, off);
            float os  = __shfl_xor(s2, off);
            s2 = fminf(fminf(s2, os), fmaxf(b, ob));
            if (ob < b || (ob == b && obi < bi)) { b = ob; bi = obi; }
        }
        if (col == 0) {
            const int row = w * 16 + quad * 4 + r;
            s_bi[row] = bi;
            if (s2 - b < 0.015f) {                  // near-tie under bf16 noise
                int p = atomicAdd(&s_nflag, 1);
                s_flag[p] = row;
            }
        }
    }
    __syncthreads();

    // exact fp32 re-argmin for flagged rows (bit-identical to verified r1 path)
    const int nf = s_nflag;
    for (int i = w; i < nf; i += 4) {
        const int row = s_flag[i];
        const size_t gr = (size_t)blockIdx.x * RPB + row;
        float4 xr4[16];
        #pragma unroll
        for (int db = 0; db < 16; ++db) xr4[db] = xv4[gr * 16 + db];
        const float xxv = s_xx[row];
        float b = __builtin_inff(); int bi = 0;
        for (int kk = 0; kk < 8; ++kk) {
            const int k = lane * 8 + kk;
            float dot0 = 0.f, dot1 = 0.f;
            #pragma unroll
            for (int db = 0; db < 16; ++db) {
                float4 cq = cbv4[k * 16 + db];
                dot0 = fmaf(xr4[db].x, cq.x, dot0);
                dot1 = fmaf(xr4[db].y, cq.y, dot1);
                dot0 = fmaf(xr4[db].z, cq.z, dot0);
                dot1 = fmaf(xr4[db].w, cq.w, dot1);
            }
            const float dist = (xxv - 2.f * (dot0 + dot1)) + s_cc[k];
            if (dist < b) { b = dist; bi = k; }
        }
        #pragma unroll
        for (int off = 1; off < 64; off <<= 1) {
            float ob  = __shfl_xor(b, off);
            int   obi = __shfl_xor(bi, off);
            if (ob < b || (ob == b && obi < bi)) { b = ob; bi = obi; }
        }
        if (lane == 0) s_bi[row] = bi;
    }
    __syncthreads();

    // coalesced gather+store (validated r2/r4/r5)
    float4* outv = (float4*)out + (size_t)blockIdx.x * (RPB * 16);
    #pragma unroll
    for (int j = 0; j < RPB * 16 / BLOCK; ++j) {
        const int f4 = j * BLOCK + t;
        const int r  = f4 >> 4;
        const int q  = f4 & 15;
        outv[f4] = cbv4[s_bi[r] * 16 + q];
    }
}

extern "C" void kernel_launch(void* const* d_in, const int* in_sizes, int n_in,
                              void* d_out, int out_size, void* d_ws, size_t ws_size,
                              hipStream_t stream) {
    const float* x  = (const float*)d_in[0];   // 131072 x 64
    const float* cb = (const float*)d_in[1];   // 512 x 64
    float* out = (float*)d_out;

    unsigned short* wh = (unsigned short*)d_ws;                  // 64 KB
    float*          cc = (float*)((char*)d_ws + 65536);          // 2 KB

    vq_prep<<<2, 256, 0, stream>>>(cb, wh, cc);

    const int N = in_sizes[0] / D;             // 131072
    vq_mfma<<<N / RPB, BLOCK, 0, stream>>>(x, cb, wh, cc, out);
}

// Round 7
// 335.819 us; speedup vs baseline: 2.0917x; 2.0917x over previous
//
#include <hip/hip_runtime.h>

#define D 64
#define KCODES 512
#define BLOCK 256
#define RPB 64           // rows per block (4 waves x 16 rows) -> grid 2048
#define CHUNK 64         // codes staged in LDS per iteration (8 KB)
#define NCHUNK (KCODES / CHUNK)

typedef short  short8  __attribute__((ext_vector_type(8)));
typedef float  f32x4   __attribute__((ext_vector_type(4)));

__device__ __forceinline__ unsigned short bf16rne(float f) {
    union { float f; unsigned u; } a; a.f = f;
    unsigned r = a.u + 0x7FFFu + ((a.u >> 16) & 1u);
    return (unsigned short)(r >> 16);
}

// prep: cc[k]=||c_k||^2 (round-1 fma order) + bf16(-2c) into ws.
// wh layout = [chunk][seg][code][8 shorts] so main-kernel staging is a straight
// copy and LDS banking is structural-min for both writes and B-frag reads.
__global__ __launch_bounds__(256) void vq_prep(const float* __restrict__ cb,
                                               unsigned short* __restrict__ wh,
                                               float* __restrict__ cc) {
    const int k = blockIdx.x * 256 + threadIdx.x;
    if (k >= KCODES) return;
    const int chunk = k >> 6, code = k & 63;
    unsigned short* wk = wh + chunk * (CHUNK * D);
    const float4* cv = (const float4*)(cb + k * D);
    float s = 0.f;
    #pragma unroll
    for (int db = 0; db < 16; ++db) {
        float4 q = cv[db];
        s = fmaf(q.x, q.x, s); s = fmaf(q.y, q.y, s);
        s = fmaf(q.z, q.z, s); s = fmaf(q.w, q.w, s);
        const int seg = db >> 1, j0 = (db & 1) * 4;
        unsigned short* dst = wk + (seg * 64 + code) * 8 + j0;
        dst[0] = bf16rne(-2.f * q.x);
        dst[1] = bf16rne(-2.f * q.y);
        dst[2] = bf16rne(-2.f * q.z);
        dst[3] = bf16rne(-2.f * q.w);
    }
    cc[k] = s;
}

__global__ __launch_bounds__(BLOCK, 4) void vq_mfma(const float* __restrict__ x,
                                                    const float* __restrict__ cb,
                                                    const unsigned short* __restrict__ wh,
                                                    const float* __restrict__ ccg,
                                                    float* __restrict__ out) {
    __shared__ short8 s_cb[CHUNK * 8];              // [seg][code] 16B units, 8 KB
    __shared__ float s_cc[KCODES];                  // 2 KB
    __shared__ float s_xx[RPB];
    __shared__ int   s_bi[RPB];
    __shared__ int   s_flag[RPB];
    __shared__ int   s_nflag;

    const int t    = threadIdx.x;
    const int w    = t >> 6;
    const int lane = t & 63;
    const int quad = lane >> 4;
    const int col  = lane & 15;
    const float4* xv4  = (const float4*)x;
    const float4* cbv4 = (const float4*)cb;

    if (t == 0) s_nflag = 0;

    // A-fragment (validated r4-r6): m = lane&15, d = kt*32 + quad*8 + j.
    short8 xh[2];
    {
        const size_t row = (size_t)blockIdx.x * RPB + w * 16 + col;
        #pragma unroll
        for (int kt = 0; kt < 2; ++kt) {
            float4 p0 = xv4[row * 16 + kt * 8 + quad * 2];
            float4 p1 = xv4[row * 16 + kt * 8 + quad * 2 + 1];
            short8 h;
            h[0] = (short)bf16rne(p0.x); h[1] = (short)bf16rne(p0.y);
            h[2] = (short)bf16rne(p0.z); h[3] = (short)bf16rne(p0.w);
            h[4] = (short)bf16rne(p1.x); h[5] = (short)bf16rne(p1.y);
            h[6] = (short)bf16rne(p1.z); h[7] = (short)bf16rne(p1.w);
            xh[kt] = h;
        }
    }

    // wave 0: xx per row (round-1 exact order); waves 1-2: stage cc.
    if (t < RPB) {
        const size_t gr = (size_t)blockIdx.x * RPB + t;
        float s = 0.f;
        #pragma unroll
        for (int db = 0; db < 16; ++db) {
            float4 q = xv4[gr * 16 + db];
            s = fmaf(q.x, q.x, s); s = fmaf(q.y, q.y, s);
            s = fmaf(q.z, q.z, s); s = fmaf(q.w, q.w, s);
        }
        s_xx[t] = s;
    } else if (t < RPB + 128) {
        const int k4 = (t - RPB) * 4;
        *(float4*)&s_cc[k4] = *(const float4*)&ccg[k4];
    }
    __syncthreads();

    float xxr[4];
    #pragma unroll
    for (int r = 0; r < 4; ++r) xxr[r] = s_xx[w * 16 + quad * 4 + r];

    float best[4], second[4]; int bis[4];
    #pragma unroll
    for (int i = 0; i < 4; ++i) { best[i] = __builtin_inff(); second[i] = __builtin_inff(); bis[i] = 0; }

    for (int c = 0; c < NCHUNK; ++c) {
        if (c) __syncthreads();
        // stage 64 codes: straight copy of 512 16B units (prep already reordered)
        const short8* gh = (const short8*)wh + c * 512;
        s_cb[t]       = gh[t];
        s_cb[t + 256] = gh[t + 256];
        __syncthreads();

        #pragma unroll 2
        for (int ct = 0; ct < CHUNK / 16; ++ct) {
            const int lc = ct * 16 + col;              // B layout: n = lane&15
            short8 ch0 = s_cb[quad * 64 + lc];         // d = quad*8+j
            short8 ch1 = s_cb[(4 + quad) * 64 + lc];   // d = 32+quad*8+j
            const int   kglob = c * CHUNK + lc;
            const float cck   = s_cc[kglob];

            f32x4 acc;
            #pragma unroll
            for (int r = 0; r < 4; ++r) acc[r] = xxr[r] + cck;
            // dist ~= (xx+cc) + sum(bf16(-2c)*bf16(x)); 6sig err ~8e-3,
            // tau=1.5e-2 near-ties go to the exact fp32 path (validated r6).
            acc = __builtin_amdgcn_mfma_f32_16x16x32_bf16(xh[0], ch0, acc, 0, 0, 0);
            acc = __builtin_amdgcn_mfma_f32_16x16x32_bf16(xh[1], ch1, acc, 0, 0, 0);

            #pragma unroll
            for (int r = 0; r < 4; ++r) {
                const float dist = acc[r];
                second[r] = fminf(second[r], fmaxf(best[r], dist));
                if (dist < best[r]) { best[r] = dist; bis[r] = kglob; }
            }
        }
    }

    // argmin across the 16 code-lanes per row (validated r4-r6)
    #pragma unroll
    for (int r = 0; r < 4; ++r) {
        float b = best[r], s2 = second[r]; int bi = bis[r];
        #pragma unroll
        for (int off = 1; off < 16; off <<= 1) {
            float ob  = __shfl_xor(b, off);
            int   obi = __shfl_xor(bi, off);
            float os  = __shfl_xor(s2, off);
            s2 = fminf(fminf(s2, os), fmaxf(b, ob));
            if (ob < b || (ob == b && obi < bi)) { b = ob; bi = obi; }
        }
        if (col == 0) {
            const int row = w * 16 + quad * 4 + r;
            s_bi[row] = bi;
            if (s2 - b < 0.015f) {
                int p = atomicAdd(&s_nflag, 1);
                s_flag[p] = row;
            }
        }
    }
    __syncthreads();

    // exact fp32 re-argmin for flagged rows. LOOP-INVERTED (outer db, inner k):
    // x is consumed per-db so nothing can be hoisted into a 64-reg array —
    // peak state ~30 VGPRs. Per-code fma chains are d-ascending even/odd,
    // bit-identical to the validated r1 exact path.
    const int nf = s_nflag;
    for (int i = w; i < nf; i += 4) {
        const int row = s_flag[i];
        const size_t gr = (size_t)blockIdx.x * RPB + row;
        const float xxv = s_xx[row];
        float dot0[8], dot1[8];
        #pragma unroll
        for (int kk = 0; kk < 8; ++kk) { dot0[kk] = 0.f; dot1[kk] = 0.f; }
        for (int db = 0; db < 16; ++db) {
            const float4 xq = xv4[gr * 16 + db];
            #pragma unroll
            for (int kk = 0; kk < 8; ++kk) {
                const float4 cq = cbv4[(lane * 8 + kk) * 16 + db];
                dot0[kk] = fmaf(xq.x, cq.x, dot0[kk]);
                dot1[kk] = fmaf(xq.y, cq.y, dot1[kk]);
                dot0[kk] = fmaf(xq.z, cq.z, dot0[kk]);
                dot1[kk] = fmaf(xq.w, cq.w, dot1[kk]);
            }
        }
        float b = __builtin_inff(); int bi = 0;
        #pragma unroll
        for (int kk = 0; kk < 8; ++kk) {
            const int k = lane * 8 + kk;
            const float dist = (xxv - 2.f * (dot0[kk] + dot1[kk])) + s_cc[k];
            if (dist < b) { b = dist; bi = k; }
        }
        #pragma unroll
        for (int off = 1; off < 64; off <<= 1) {
            float ob  = __shfl_xor(b, off);
            int   obi = __shfl_xor(bi, off);
            if (ob < b || (ob == b && obi < bi)) { b = ob; bi = obi; }
        }
        if (lane == 0) s_bi[row] = bi;
    }
    __syncthreads();

    // coalesced gather+store (validated r2/r4-r6)
    float4* outv = (float4*)out + (size_t)blockIdx.x * (RPB * 16);
    #pragma unroll
    for (int j = 0; j < RPB * 16 / BLOCK; ++j) {
        const int f4 = j * BLOCK + t;
        const int r  = f4 >> 4;
        const int q  = f4 & 15;
        outv[f4] = cbv4[s_bi[r] * 16 + q];
    }
}

extern "C" void kernel_launch(void* const* d_in, const int* in_sizes, int n_in,
                              void* d_out, int out_size, void* d_ws, size_t ws_size,
                              hipStream_t stream) {
    const float* x  = (const float*)d_in[0];   // 131072 x 64
    const float* cb = (const float*)d_in[1];   // 512 x 64
    float* out = (float*)d_out;

    unsigned short* wh = (unsigned short*)d_ws;                  // 64 KB
    float*          cc = (float*)((char*)d_ws + 65536);          // 2 KB

    vq_prep<<<2, 256, 0, stream>>>(cb, wh, cc);

    const int N = in_sizes[0] / D;             // 131072
    vq_mfma<<<N / RPB, BLOCK, 0, stream>>>(x, cb, wh, cc, out);
}

// Round 8
// 244.231 us; speedup vs baseline: 2.8761x; 1.3750x over previous
//
#include <hip/hip_runtime.h>

#define D 64
#define KCODES 512
#define BLOCK 512        // 8 waves
#define RPB 128          // rows per block (8 waves x 16 rows) -> grid 1024

typedef short  short8  __attribute__((ext_vector_type(8)));
typedef float  f32x4   __attribute__((ext_vector_type(4)));

__device__ __forceinline__ unsigned short bf16rne(float f) {
    union { float f; unsigned u; } a; a.f = f;
    unsigned r = a.u + 0x7FFFu + ((a.u >> 16) & 1u);
    return (unsigned short)(r >> 16);
}

// prep: cc[k]=||c_k||^2 (round-1 fma order) + bf16(-2c) into ws.
// wh layout = [seg 0..7][code 0..511][8 shorts]: seg covers d = seg*8..seg*8+7.
// Main-kernel staging is then a straight coalesced copy, LDS reads conflict-free.
__global__ __launch_bounds__(256) void vq_prep(const float* __restrict__ cb,
                                               unsigned short* __restrict__ wh,
                                               float* __restrict__ cc) {
    const int k = blockIdx.x * 256 + threadIdx.x;
    if (k >= KCODES) return;
    const float4* cv = (const float4*)(cb + k * D);
    float s = 0.f;
    #pragma unroll
    for (int db = 0; db < 16; ++db) {
        float4 q = cv[db];
        s = fmaf(q.x, q.x, s); s = fmaf(q.y, q.y, s);
        s = fmaf(q.z, q.z, s); s = fmaf(q.w, q.w, s);
        const int seg = db >> 1, j0 = (db & 1) * 4;
        unsigned short* dst = wh + ((size_t)(seg * KCODES + k)) * 8 + j0;
        dst[0] = bf16rne(-2.f * q.x);
        dst[1] = bf16rne(-2.f * q.y);
        dst[2] = bf16rne(-2.f * q.z);
        dst[3] = bf16rne(-2.f * q.w);
    }
    cc[k] = s;
}

__global__ __launch_bounds__(BLOCK, 4) void vq_mfma(const float* __restrict__ x,
                                                    const float* __restrict__ cb,
                                                    const unsigned short* __restrict__ wh,
                                                    const float* __restrict__ ccg,
                                                    float* __restrict__ out) {
    __shared__ short8 s_cb[8 * KCODES];             // [seg][code] 16B units, 64 KB
    __shared__ float s_cc[KCODES];                  // 2 KB
    __shared__ float s_xx[RPB];
    __shared__ int   s_bi[RPB];
    __shared__ int   s_flag[RPB];
    __shared__ int   s_nflag;

    const int t    = threadIdx.x;
    const int w    = t >> 6;        // wave 0..7
    const int lane = t & 63;
    const int quad = lane >> 4;
    const int col  = lane & 15;
    const float4* xv4  = (const float4*)x;
    const float4* cbv4 = (const float4*)cb;

    if (t == 0) s_nflag = 0;

    // Stage the ENTIRE codebook once: 4096 16B units, 8 per thread, coalesced.
    // After the one barrier below, the k-loop touches no global memory and no
    // barriers (r7's 8x staging/barrier ladder was the 90% stall).
    {
        const short8* gh = (const short8*)wh;
        #pragma unroll
        for (int i = 0; i < 8; ++i) s_cb[i * BLOCK + t] = gh[i * BLOCK + t];
    }

    // A-fragment (validated r4-r7): m = lane&15, d = kt*32 + quad*8 + j.
    short8 xh[2];
    {
        const size_t row = (size_t)blockIdx.x * RPB + w * 16 + col;
        #pragma unroll
        for (int kt = 0; kt < 2; ++kt) {
            float4 p0 = xv4[row * 16 + kt * 8 + quad * 2];
            float4 p1 = xv4[row * 16 + kt * 8 + quad * 2 + 1];
            short8 h;
            h[0] = (short)bf16rne(p0.x); h[1] = (short)bf16rne(p0.y);
            h[2] = (short)bf16rne(p0.z); h[3] = (short)bf16rne(p0.w);
            h[4] = (short)bf16rne(p1.x); h[5] = (short)bf16rne(p1.y);
            h[6] = (short)bf16rne(p1.z); h[7] = (short)bf16rne(p1.w);
            xh[kt] = h;
        }
    }

    // waves 0-1: xx per row (round-1 exact order); wave 2: stage cc.
    if (t < RPB) {
        const size_t gr = (size_t)blockIdx.x * RPB + t;
        float s = 0.f;
        #pragma unroll
        for (int db = 0; db < 16; ++db) {
            float4 q = xv4[gr * 16 + db];
            s = fmaf(q.x, q.x, s); s = fmaf(q.y, q.y, s);
            s = fmaf(q.z, q.z, s); s = fmaf(q.w, q.w, s);
        }
        s_xx[t] = s;
    } else if (t < RPB + 128) {
        const int k4 = (t - RPB) * 4;
        *(float4*)&s_cc[k4] = *(const float4*)&ccg[k4];
    }
    __syncthreads();    // the ONLY pre-epilogue barrier

    float xxr[4];
    #pragma unroll
    for (int r = 0; r < 4; ++r) xxr[r] = s_xx[w * 16 + quad * 4 + r];

    float best[4], second[4]; int bis[4];
    #pragma unroll
    for (int i = 0; i < 4; ++i) { best[i] = __builtin_inff(); second[i] = __builtin_inff(); bis[i] = 0; }

    // Barrier-free k-loop over all 512 codes: 2 ds_read_b128 + 2 MFMA + cmp per ct.
    #pragma unroll 4
    for (int ct = 0; ct < KCODES / 16; ++ct) {
        const int k = ct * 16 + col;               // B layout: n = lane&15
        short8 ch0 = s_cb[quad * KCODES + k];      // d = quad*8+j
        short8 ch1 = s_cb[(4 + quad) * KCODES + k];// d = 32+quad*8+j
        const float cck = s_cc[k];

        f32x4 acc;
        #pragma unroll
        for (int r = 0; r < 4; ++r) acc[r] = xxr[r] + cck;
        // dist ~= (xx+cc) + sum(bf16(-2c)*bf16(x)); 6sig err ~8e-3,
        // tau=1.5e-2 near-ties go to the exact fp32 path (validated r6/r7).
        acc = __builtin_amdgcn_mfma_f32_16x16x32_bf16(xh[0], ch0, acc, 0, 0, 0);
        acc = __builtin_amdgcn_mfma_f32_16x16x32_bf16(xh[1], ch1, acc, 0, 0, 0);

        #pragma unroll
        for (int r = 0; r < 4; ++r) {
            const float dist = acc[r];
            second[r] = fminf(second[r], fmaxf(best[r], dist));
            if (dist < best[r]) { best[r] = dist; bis[r] = k; }
        }
    }

    // argmin across the 16 code-lanes per row (validated r4-r7)
    #pragma unroll
    for (int r = 0; r < 4; ++r) {
        float b = best[r], s2 = second[r]; int bi = bis[r];
        #pragma unroll
        for (int off = 1; off < 16; off <<= 1) {
            float ob  = __shfl_xor(b, off);
            int   obi = __shfl_xor(bi, off);
            float os  = __shfl_xor(s2, off);
            s2 = fminf(fminf(s2, os), fmaxf(b, ob));
            if (ob < b || (ob == b && obi < bi)) { b = ob; bi = obi; }
        }
        if (col == 0) {
            const int row = w * 16 + quad * 4 + r;
            s_bi[row] = bi;
            if (s2 - b < 0.015f) {
                int p = atomicAdd(&s_nflag, 1);
                s_flag[p] = row;
            }
        }
    }
    __syncthreads();

    // exact fp32 re-argmin for flagged rows, loop-inverted thin form
    // (validated r7: bit-identical distances to the r1 exact path, ~30 VGPRs).
    const int nf = s_nflag;
    for (int i = w; i < nf; i += 8) {
        const int row = s_flag[i];
        const size_t gr = (size_t)blockIdx.x * RPB + row;
        const float xxv = s_xx[row];
        float dot0[8], dot1[8];
        #pragma unroll
        for (int kk = 0; kk < 8; ++kk) { dot0[kk] = 0.f; dot1[kk] = 0.f; }
        for (int db = 0; db < 16; ++db) {
            const float4 xq = xv4[gr * 16 + db];
            #pragma unroll
            for (int kk = 0; kk < 8; ++kk) {
                const float4 cq = cbv4[(lane * 8 + kk) * 16 + db];
                dot0[kk] = fmaf(xq.x, cq.x, dot0[kk]);
                dot1[kk] = fmaf(xq.y, cq.y, dot1[kk]);
                dot0[kk] = fmaf(xq.z, cq.z, dot0[kk]);
                dot1[kk] = fmaf(xq.w, cq.w, dot1[kk]);
            }
        }
        float b = __builtin_inff(); int bi = 0;
        #pragma unroll
        for (int kk = 0; kk < 8; ++kk) {
            const int k = lane * 8 + kk;
            const float dist = (xxv - 2.f * (dot0[kk] + dot1[kk])) + s_cc[k];
            if (dist < b) { b = dist; bi = k; }
        }
        #pragma unroll
        for (int off = 1; off < 64; off <<= 1) {
            float ob  = __shfl_xor(b, off);
            int   obi = __shfl_xor(bi, off);
            if (ob < b || (ob == b && obi < bi)) { b = ob; bi = obi; }
        }
        if (lane == 0) s_bi[row] = bi;
    }
    __syncthreads();

    // coalesced gather+store (validated r2/r4-r7)
    float4* outv = (float4*)out + (size_t)blockIdx.x * (RPB * 16);
    #pragma unroll
    for (int j = 0; j < RPB * 16 / BLOCK; ++j) {
        const int f4 = j * BLOCK + t;
        const int r  = f4 >> 4;
        const int q  = f4 & 15;
        outv[f4] = cbv4[s_bi[r] * 16 + q];
    }
}

extern "C" void kernel_launch(void* const* d_in, const int* in_sizes, int n_in,
                              void* d_out, int out_size, void* d_ws, size_t ws_size,
                              hipStream_t stream) {
    const float* x  = (const float*)d_in[0];   // 131072 x 64
    const float* cb = (const float*)d_in[1];   // 512 x 64
    float* out = (float*)d_out;

    unsigned short* wh = (unsigned short*)d_ws;                  // 64 KB
    float*          cc = (float*)((char*)d_ws + 65536);          // 2 KB

    vq_prep<<<2, 256, 0, stream>>>(cb, wh, cc);

    const int N = in_sizes[0] / D;             // 131072
    vq_mfma<<<N / RPB, BLOCK, 0, stream>>>(x, cb, wh, cc, out);
}

// Round 9
// 142.184 us; speedup vs baseline: 4.9403x; 1.7177x over previous
//
#include <hip/hip_runtime.h>

#define D 64
#define KCODES 512
#define BLOCK 1024       // 16 waves
#define RPB 256          // rows per block (16 waves x 16 rows) -> grid 512

typedef short  short8  __attribute__((ext_vector_type(8)));
typedef float  f32x4   __attribute__((ext_vector_type(4)));

__device__ __forceinline__ unsigned short bf16rne(float f) {
    union { float f; unsigned u; } a; a.f = f;
    unsigned r = a.u + 0x7FFFu + ((a.u >> 16) & 1u);
    return (unsigned short)(r >> 16);
}
__device__ __forceinline__ void bf16_split(float f, unsigned short& h, unsigned short& l) {
    h = bf16rne(f);
    union { unsigned u; float f; } b; b.u = (unsigned)h << 16;
    l = bf16rne(f - b.f);
}

// prep: cc[k]=||c_k||^2 (round-1 fma order) + bf16 hi/lo of (-2c) into ws.
// layout = [seg 0..7][code 0..511][8 shorts], seg covers d = seg*8..seg*8+7:
// main-kernel staging is a straight coalesced copy; LDS reads conflict-minimal.
__global__ __launch_bounds__(256) void vq_prep(const float* __restrict__ cb,
                                               unsigned short* __restrict__ wh,
                                               unsigned short* __restrict__ wl,
                                               float* __restrict__ cc) {
    const int k = blockIdx.x * 256 + threadIdx.x;
    if (k >= KCODES) return;
    const float4* cv = (const float4*)(cb + k * D);
    float s = 0.f;
    #pragma unroll
    for (int db = 0; db < 16; ++db) {
        float4 q = cv[db];
        s = fmaf(q.x, q.x, s); s = fmaf(q.y, q.y, s);
        s = fmaf(q.z, q.z, s); s = fmaf(q.w, q.w, s);
        const int seg = db >> 1, j0 = (db & 1) * 4;
        const size_t o = ((size_t)(seg * KCODES + k)) * 8 + j0;
        float v[4] = {q.x, q.y, q.z, q.w};
        #pragma unroll
        for (int j = 0; j < 4; ++j) {
            unsigned short h, l;
            bf16_split(-2.f * v[j], h, l);
            wh[o + j] = h; wl[o + j] = l;
        }
    }
    cc[k] = s;
}

__global__ __launch_bounds__(BLOCK, 4) void vq_mfma(const float* __restrict__ x,
                                                    const float* __restrict__ cb,
                                                    const unsigned short* __restrict__ wh,
                                                    const unsigned short* __restrict__ wl,
                                                    const float* __restrict__ ccg,
                                                    float* __restrict__ out) {
    __shared__ short8 s_cbh[8 * KCODES];            // 64 KB [seg][code]
    __shared__ short8 s_cbl[8 * KCODES];            // 64 KB
    __shared__ float s_cc[KCODES];                  // 2 KB
    __shared__ float s_xx[RPB];
    __shared__ int   s_bi[RPB];
    __shared__ int   s_flag[RPB];
    __shared__ int   s_nflag;

    const int t    = threadIdx.x;
    const int w    = t >> 6;        // wave 0..15
    const int lane = t & 63;
    const int quad = lane >> 4;
    const int col  = lane & 15;
    const float4* xv4  = (const float4*)x;
    const float4* cbv4 = (const float4*)cb;

    if (t == 0) s_nflag = 0;

    // Stage hi+lo codebooks once: 2 x 4096 16B units, coalesced.
    {
        const short8* gh = (const short8*)wh;
        const short8* gl = (const short8*)wl;
        #pragma unroll
        for (int i = 0; i < 4; ++i) {
            s_cbh[i * BLOCK + t] = gh[i * BLOCK + t];
            s_cbl[i * BLOCK + t] = gl[i * BLOCK + t];
        }
    }
    if (t < 128) *(float4*)&s_cc[t * 4] = *(const float4*)&ccg[t * 4];

    // A-fragment (validated r4-r8): m = lane&15, d = kt*32 + quad*8 + j.
    // Keep the fp32 values to derive xx without a separate divergent load phase.
    short8 xh[2], xl[2];
    float ssq = 0.f;
    {
        const size_t row = (size_t)blockIdx.x * RPB + w * 16 + col;
        #pragma unroll
        for (int kt = 0; kt < 2; ++kt) {
            float4 p0 = xv4[row * 16 + kt * 8 + quad * 2];
            float4 p1 = xv4[row * 16 + kt * 8 + quad * 2 + 1];
            float v[8] = {p0.x, p0.y, p0.z, p0.w, p1.x, p1.y, p1.z, p1.w};
            short8 hh, ll;
            #pragma unroll
            for (int j = 0; j < 8; ++j) {
                unsigned short h, l;
                bf16_split(v[j], h, l);
                hh[j] = (short)h; ll[j] = (short)l;
                ssq = fmaf(v[j], v[j], ssq);
            }
            xh[kt] = hh; xl[kt] = ll;
        }
        // reduce ssq across the 4 quads holding this row's d-chunks
        ssq += __shfl_xor(ssq, 16);
        ssq += __shfl_xor(ssq, 32);
        if (quad == 0) s_xx[w * 16 + col] = ssq;
    }
    __syncthreads();    // codebook + cc + xx ready; k-loop is barrier-free

    float xxr[4];
    #pragma unroll
    for (int r = 0; r < 4; ++r) xxr[r] = s_xx[w * 16 + quad * 4 + r];

    float best[4], second[4]; int bis[4];
    #pragma unroll
    for (int i = 0; i < 4; ++i) { best[i] = __builtin_inff(); second[i] = __builtin_inff(); bis[i] = 0; }

    // Barrier-free k-loop, 3-term split product (r5-validated numerics):
    // dist = (xx+cc) + [xh*ch + xl*ch + xh*cl], err ~1e-5 -> tau=1e-3.
    #pragma unroll 4
    for (int ct = 0; ct < KCODES / 16; ++ct) {
        const int k = ct * 16 + col;                // B layout: n = lane&15
        short8 ch0 = s_cbh[quad * KCODES + k];      // d = quad*8+j
        short8 ch1 = s_cbh[(4 + quad) * KCODES + k];
        short8 cl0 = s_cbl[quad * KCODES + k];
        short8 cl1 = s_cbl[(4 + quad) * KCODES + k];
        const float cck = s_cc[k];

        f32x4 acc;
        #pragma unroll
        for (int r = 0; r < 4; ++r) acc[r] = xxr[r] + cck;
        acc = __builtin_amdgcn_mfma_f32_16x16x32_bf16(xh[0], ch0, acc, 0, 0, 0);
        acc = __builtin_amdgcn_mfma_f32_16x16x32_bf16(xl[0], ch0, acc, 0, 0, 0);
        acc = __builtin_amdgcn_mfma_f32_16x16x32_bf16(xh[0], cl0, acc, 0, 0, 0);
        acc = __builtin_amdgcn_mfma_f32_16x16x32_bf16(xh[1], ch1, acc, 0, 0, 0);
        acc = __builtin_amdgcn_mfma_f32_16x16x32_bf16(xl[1], ch1, acc, 0, 0, 0);
        acc = __builtin_amdgcn_mfma_f32_16x16x32_bf16(xh[1], cl1, acc, 0, 0, 0);

        #pragma unroll
        for (int r = 0; r < 4; ++r) {
            const float dist = acc[r];
            second[r] = fminf(second[r], fmaxf(best[r], dist));
            if (dist < best[r]) { best[r] = dist; bis[r] = k; }
        }
    }

    // argmin across the 16 code-lanes per row (validated r4-r8)
    #pragma unroll
    for (int r = 0; r < 4; ++r) {
        float b = best[r], s2 = second[r]; int bi = bis[r];
        #pragma unroll
        for (int off = 1; off < 16; off <<= 1) {
            float ob  = __shfl_xor(b, off);
            int   obi = __shfl_xor(bi, off);
            float os  = __shfl_xor(s2, off);
            s2 = fminf(fminf(s2, os), fmaxf(b, ob));
            if (ob < b || (ob == b && obi < bi)) { b = ob; bi = obi; }
        }
        if (col == 0) {
            const int row = w * 16 + quad * 4 + r;
            s_bi[row] = bi;
            if (s2 - b < 1e-3f) {                   // 3-term err << 1e-3 (r5)
                int p = atomicAdd(&s_nflag, 1);
                s_flag[p] = row;
            }
        }
    }
    __syncthreads();

    // exact fp32 re-argmin, thin inverted form (validated r7/r8). ~0.3% of
    // rows now -> the divergent TA cost that dominated r6-r8 is ~gone.
    const int nf = s_nflag;
    for (int i = w; i < nf; i += 16) {
        const int row = s_flag[i];
        const size_t gr = (size_t)blockIdx.x * RPB + row;
        const float xxv = s_xx[row];
        float dot0[8], dot1[8];
        #pragma unroll
        for (int kk = 0; kk < 8; ++kk) { dot0[kk] = 0.f; dot1[kk] = 0.f; }
        for (int db = 0; db < 16; ++db) {
            const float4 xq = xv4[gr * 16 + db];
            #pragma unroll
            for (int kk = 0; kk < 8; ++kk) {
                const float4 cq = cbv4[(lane * 8 + kk) * 16 + db];
                dot0[kk] = fmaf(xq.x, cq.x, dot0[kk]);
                dot1[kk] = fmaf(xq.y, cq.y, dot1[kk]);
                dot0[kk] = fmaf(xq.z, cq.z, dot0[kk]);
                dot1[kk] = fmaf(xq.w, cq.w, dot1[kk]);
            }
        }
        float b = __builtin_inff(); int bi = 0;
        #pragma unroll
        for (int kk = 0; kk < 8; ++kk) {
            const int k = lane * 8 + kk;
            const float dist = (xxv - 2.f * (dot0[kk] + dot1[kk])) + s_cc[k];
            if (dist < b) { b = dist; bi = k; }
        }
        #pragma unroll
        for (int off = 1; off < 64; off <<= 1) {
            float ob  = __shfl_xor(b, off);
            int   obi = __shfl_xor(bi, off);
            if (ob < b || (ob == b && obi < bi)) { b = ob; bi = obi; }
        }
        if (lane == 0) s_bi[row] = bi;
    }
    __syncthreads();

    // coalesced gather+store (validated r2/r4-r8)
    float4* outv = (float4*)out + (size_t)blockIdx.x * (RPB * 16);
    #pragma unroll
    for (int j = 0; j < RPB * 16 / BLOCK; ++j) {
        const int f4 = j * BLOCK + t;
        const int r  = f4 >> 4;
        const int q  = f4 & 15;
        outv[f4] = cbv4[s_bi[r] * 16 + q];
    }
}

extern "C" void kernel_launch(void* const* d_in, const int* in_sizes, int n_in,
                              void* d_out, int out_size, void* d_ws, size_t ws_size,
                              hipStream_t stream) {
    const float* x  = (const float*)d_in[0];   // 131072 x 64
    const float* cb = (const float*)d_in[1];   // 512 x 64
    float* out = (float*)d_out;

    unsigned short* wh = (unsigned short*)d_ws;                  // 64 KB
    unsigned short* wl = (unsigned short*)((char*)d_ws + 65536); // 64 KB
    float*          cc = (float*)((char*)d_ws + 131072);         // 2 KB

    vq_prep<<<2, 256, 0, stream>>>(cb, wh, wl, cc);

    const int N = in_sizes[0] / D;             // 131072
    vq_mfma<<<N / RPB, BLOCK, 0, stream>>>(x, cb, wh, wl, cc, out);
}

// Round 10
// 133.505 us; speedup vs baseline: 5.2615x; 1.0650x over previous
//
#include <hip/hip_runtime.h>

#define D 64
#define KCODES 512
#define BLOCK 1024       // 16 waves
#define RPB 512          // rows per block (16 waves x 32 rows) -> grid 256 = 1/CU
#define SSTR 513         // seg stride in 16B units: 512+1 pad breaks seg-bank collision

typedef short  short4_ __attribute__((ext_vector_type(4)));
typedef short  short8  __attribute__((ext_vector_type(8)));
typedef float  f32x4   __attribute__((ext_vector_type(4)));

__device__ __forceinline__ unsigned short bf16rne(float f) {
    union { float f; unsigned u; } a; a.f = f;
    unsigned r = a.u + 0x7FFFu + ((a.u >> 16) & 1u);
    return (unsigned short)(r >> 16);
}
__device__ __forceinline__ void bf16_split(float f, unsigned short& h, unsigned short& l) {
    h = bf16rne(f);
    union { unsigned u; float f; } b; b.u = (unsigned)h << 16;
    l = bf16rne(f - b.f);
}

// Single kernel: codebook split + cc + GEMM-argmin + hedge + gather.
__global__ __launch_bounds__(BLOCK, 4) void vq_mfma(const float* __restrict__ x,
                                                    const float* __restrict__ cb,
                                                    float* __restrict__ out) {
    __shared__ short8 s_cbh[8 * SSTR];              // [seg][code] 16B units (+pad)
    __shared__ short8 s_cbl[8 * SSTR];
    __shared__ float s_cc[KCODES];
    __shared__ float s_xx[RPB];
    __shared__ int   s_bi[RPB];
    __shared__ int   s_flag[RPB];
    __shared__ int   s_nflag;

    const int t    = threadIdx.x;
    const int w    = t >> 6;        // wave 0..15
    const int lane = t & 63;
    const int quad = lane >> 4;
    const int col  = lane & 15;
    const float4* xv4  = (const float4*)x;
    const float4* cbv4 = (const float4*)cb;

    if (t == 0) s_nflag = 0;

    // Prologue A (replaces the vq_prep dispatch — r9's ~68us of prep+launch):
    // coalesced cb float4 loads; in-register bf16 hi/lo split of (-2c) into
    // LDS [seg][code] layout; cc via 16-lane shuffle tree (same validated
    // order-change class as r9's xx tree).
    #pragma unroll
    for (int i = 0; i < 8; ++i) {
        const int e  = i * BLOCK + t;       // 0..8191 = (code, db) pairs
        const int k  = e >> 4;
        const int db = e & 15;              // == t & 15
        const int seg = db >> 1, j0 = (db & 1) * 4;
        const float4 q = cbv4[e];
        short4_ hh, ll;
        {
            unsigned short h, l;
            bf16_split(-2.f * q.x, h, l); hh[0] = (short)h; ll[0] = (short)l;
            bf16_split(-2.f * q.y, h, l); hh[1] = (short)h; ll[1] = (short)l;
            bf16_split(-2.f * q.z, h, l); hh[2] = (short)h; ll[2] = (short)l;
            bf16_split(-2.f * q.w, h, l); hh[3] = (short)h; ll[3] = (short)l;
        }
        *(short4_*)((short*)&s_cbh[seg * SSTR + k] + j0) = hh;
        *(short4_*)((short*)&s_cbl[seg * SSTR + k] + j0) = ll;
        // cc partial: 4-square chain, then xor-tree over the 16 lanes of code k
        float p = fmaf(q.x, q.x, 0.f);
        p = fmaf(q.y, q.y, p); p = fmaf(q.z, q.z, p); p = fmaf(q.w, q.w, p);
        p += __shfl_xor(p, 1); p += __shfl_xor(p, 2);
        p += __shfl_xor(p, 4); p += __shfl_xor(p, 8);
        if (db == 0) s_cc[k] = p;
    }

    // Prologue B: A-fragments for 2 row-tiles (validated r4-r9 layout:
    // m = lane&15, d = kt*32 + quad*8 + j) + xx via quad-shuffle tree (r9).
    short8 xh[2][2], xl[2][2];
    #pragma unroll
    for (int rt = 0; rt < 2; ++rt) {
        const size_t row = (size_t)blockIdx.x * RPB + w * 32 + rt * 16 + col;
        float ssq = 0.f;
        #pragma unroll
        for (int kt = 0; kt < 2; ++kt) {
            float4 p0 = xv4[row * 16 + kt * 8 + quad * 2];
            float4 p1 = xv4[row * 16 + kt * 8 + quad * 2 + 1];
            float v[8] = {p0.x, p0.y, p0.z, p0.w, p1.x, p1.y, p1.z, p1.w};
            short8 hh, ll;
            #pragma unroll
            for (int j = 0; j < 8; ++j) {
                unsigned short h, l;
                bf16_split(v[j], h, l);
                hh[j] = (short)h; ll[j] = (short)l;
                ssq = fmaf(v[j], v[j], ssq);
            }
            xh[rt][kt] = hh; xl[rt][kt] = ll;
        }
        ssq += __shfl_xor(ssq, 16);
        ssq += __shfl_xor(ssq, 32);
        if (quad == 0) s_xx[w * 32 + rt * 16 + col] = ssq;
    }
    __syncthreads();    // LDS codebook + cc + xx ready; k-loop barrier-free

    float xxr[8];
    #pragma unroll
    for (int rt = 0; rt < 2; ++rt)
        #pragma unroll
        for (int r = 0; r < 4; ++r)
            xxr[rt * 4 + r] = s_xx[w * 32 + rt * 16 + quad * 4 + r];

    float best[8], second[8]; int bis[8];
    #pragma unroll
    for (int i = 0; i < 8; ++i) { best[i] = __builtin_inff(); second[i] = __builtin_inff(); bis[i] = 0; }

    // Barrier-free k-loop: 4 ds_read_b128 amortized over 8 C-rows (2 tiles),
    // 2 independent 6-MFMA chains. 3-term split, tau=1e-3 (validated r9).
    #pragma unroll 2
    for (int ct = 0; ct < KCODES / 16; ++ct) {
        const int k = ct * 16 + col;                // B layout: n = lane&15
        short8 ch0 = s_cbh[quad * SSTR + k];        // d = quad*8+j
        short8 ch1 = s_cbh[(4 + quad) * SSTR + k];  // d = 32+quad*8+j
        short8 cl0 = s_cbl[quad * SSTR + k];
        short8 cl1 = s_cbl[(4 + quad) * SSTR + k];
        const float cck = s_cc[k];

        #pragma unroll
        for (int rt = 0; rt < 2; ++rt) {
            f32x4 acc;
            #pragma unroll
            for (int r = 0; r < 4; ++r) acc[r] = xxr[rt * 4 + r] + cck;
            acc = __builtin_amdgcn_mfma_f32_16x16x32_bf16(xh[rt][0], ch0, acc, 0, 0, 0);
            acc = __builtin_amdgcn_mfma_f32_16x16x32_bf16(xl[rt][0], ch0, acc, 0, 0, 0);
            acc = __builtin_amdgcn_mfma_f32_16x16x32_bf16(xh[rt][0], cl0, acc, 0, 0, 0);
            acc = __builtin_amdgcn_mfma_f32_16x16x32_bf16(xh[rt][1], ch1, acc, 0, 0, 0);
            acc = __builtin_amdgcn_mfma_f32_16x16x32_bf16(xl[rt][1], ch1, acc, 0, 0, 0);
            acc = __builtin_amdgcn_mfma_f32_16x16x32_bf16(xh[rt][1], cl1, acc, 0, 0, 0);
            #pragma unroll
            for (int r = 0; r < 4; ++r) {
                const int idx = rt * 4 + r;
                const float dist = acc[r];
                second[idx] = fminf(second[idx], fmaxf(best[idx], dist));
                if (dist < best[idx]) { best[idx] = dist; bis[idx] = k; }
            }
        }
    }

    // argmin across the 16 code-lanes per row (validated r4-r9)
    #pragma unroll
    for (int rt = 0; rt < 2; ++rt) {
        #pragma unroll
        for (int r = 0; r < 4; ++r) {
            const int idx = rt * 4 + r;
            float b = best[idx], s2 = second[idx]; int bi = bis[idx];
            #pragma unroll
            for (int off = 1; off < 16; off <<= 1) {
                float ob  = __shfl_xor(b, off);
                int   obi = __shfl_xor(bi, off);
                float os  = __shfl_xor(s2, off);
                s2 = fminf(fminf(s2, os), fmaxf(b, ob));
                if (ob < b || (ob == b && obi < bi)) { b = ob; bi = obi; }
            }
            if (col == 0) {
                const int row = w * 32 + rt * 16 + quad * 4 + r;
                s_bi[row] = bi;
                if (s2 - b < 1e-3f) {
                    int p = atomicAdd(&s_nflag, 1);
                    s_flag[p] = row;
                }
            }
        }
    }
    __syncthreads();

    // exact fp32 re-argmin, thin inverted form (validated r7-r9; ~0.3% rows)
    const int nf = s_nflag;
    for (int i = w; i < nf; i += 16) {
        const int row = s_flag[i];
        const size_t gr = (size_t)blockIdx.x * RPB + row;
        const float xxv = s_xx[row];
        float dot0[8], dot1[8];
        #pragma unroll
        for (int kk = 0; kk < 8; ++kk) { dot0[kk] = 0.f; dot1[kk] = 0.f; }
        for (int db = 0; db < 16; ++db) {
            const float4 xq = xv4[gr * 16 + db];
            #pragma unroll
            for (int kk = 0; kk < 8; ++kk) {
                const float4 cq = cbv4[(lane * 8 + kk) * 16 + db];
                dot0[kk] = fmaf(xq.x, cq.x, dot0[kk]);
                dot1[kk] = fmaf(xq.y, cq.y, dot1[kk]);
                dot0[kk] = fmaf(xq.z, cq.z, dot0[kk]);
                dot1[kk] = fmaf(xq.w, cq.w, dot1[kk]);
            }
        }
        float b = __builtin_inff(); int bi = 0;
        #pragma unroll
        for (int kk = 0; kk < 8; ++kk) {
            const int k = lane * 8 + kk;
            const float dist = (xxv - 2.f * (dot0[kk] + dot1[kk])) + s_cc[k];
            if (dist < b) { b = dist; bi = k; }
        }
        #pragma unroll
        for (int off = 1; off < 64; off <<= 1) {
            float ob  = __shfl_xor(b, off);
            int   obi = __shfl_xor(bi, off);
            if (ob < b || (ob == b && obi < bi)) { b = ob; bi = obi; }
        }
        if (lane == 0) s_bi[row] = bi;
    }
    __syncthreads();

    // coalesced gather+store (validated r2/r4-r9)
    float4* outv = (float4*)out + (size_t)blockIdx.x * (RPB * 16);
    #pragma unroll
    for (int j = 0; j < RPB * 16 / BLOCK; ++j) {
        const int f4 = j * BLOCK + t;
        const int r  = f4 >> 4;
        const int q  = f4 & 15;
        outv[f4] = cbv4[s_bi[r] * 16 + q];
    }
}

extern "C" void kernel_launch(void* const* d_in, const int* in_sizes, int n_in,
                              void* d_out, int out_size, void* d_ws, size_t ws_size,
                              hipStream_t stream) {
    const float* x  = (const float*)d_in[0];   // 131072 x 64
    const float* cb = (const float*)d_in[1];   // 512 x 64
    float* out = (float*)d_out;

    const int N = in_sizes[0] / D;             // 131072
    vq_mfma<<<N / RPB, BLOCK, 0, stream>>>(x, cb, out);
}